// Round 9
// baseline (568.393 us; speedup 1.0000x reference)
//
#include <hip/hip_runtime.h>
#include <math.h>

#define BATCH 128
#define T 250
#define D_IN 700
#define H 256
#define D_OUT 20

typedef float v2f __attribute__((ext_vector_type(2)));
typedef __attribute__((ext_vector_type(8))) short bf16x8;
typedef __attribute__((ext_vector_type(4))) float f32x4;
typedef __attribute__((ext_vector_type(4))) unsigned u32x4;

static __device__ __forceinline__ unsigned short f2b(float f) {
    unsigned u = __float_as_uint(f);
    u += 0x7FFFu + ((u >> 16) & 1u);
    return (unsigned short)(u >> 16);
}

// Raw barrier: LDS ordering only (lgkmcnt). No vmcnt drain so global loads
// stay in flight across it.
static __device__ __forceinline__ void bar() {
    asm volatile("s_waitcnt lgkmcnt(0)" ::: "memory");
    __builtin_amdgcn_s_barrier();
    asm volatile("" ::: "memory");
}

// PA partial index (planar C1 cols, 8 f32 per lane at stride 10) — R8-proven.
#define PIDX(c) (10 * ((c) >> 3) + ((c) & 7))
// PB partial index (compacted C2 cols, 4 f32 per lane at stride 6).
#define QIDX(c) (6 * ((c) >> 2) + ((c) & 3))

// ---------------------------------------------------------------------------
// Workspace layout (no U workspace any more — U is JIT-computed in LDS):
//   C1b   [257][512] bf16   row k: p<256 -> W12T[k][p]; p>=256 -> W11T[k][p-256]
//   C2b   [257][288] bf16   row k: p<256 -> W22T[k][p]; p in [256,276) -> Wo[p-256][k]; else 0
//                            (COMPACTED: R8 wasted 472 zero bytes per row)
//   Wi1p  [256][704] bf16   cols 700..703 zero (MFMA K-pad)
//   row 256 of C1b/C2b is all-zero (spike-list padding target)
//
// R9 = R8 (proven two-track skew, wave-own lists, 1 barrier/window) +
//  (a) C2 row compaction: track-B gather reads 576B rows (uint2/lane + one
//      aux dword on quad 0 for the 32 aO cols) — the window is per-CU
//      L2-port BW-bound (80 B/cy measured), so bytes are the lever.
//  (b) JIT-U fusion: each block MFMAs its own next 16-step U chunk
//      (x 16x704 @ Wi1p^T) spread over the windows, into an LDS double
//      buffer — kills the separate gemm_u dispatch and U's HBM round-trip.
// ---------------------------------------------------------------------------
#define N_C1 (257 * 512)
#define N_C2 (257 * 288)
#define N_WP (256 * 704)

__global__ void prep_k(const float* __restrict__ Wi1, const float* __restrict__ W11,
                       const float* __restrict__ W12, const float* __restrict__ W22,
                       const float* __restrict__ Wo,
                       unsigned short* __restrict__ Wi1p, unsigned short* __restrict__ C1,
                       unsigned short* __restrict__ C2) {
    int idx = blockIdx.x * 256 + threadIdx.x;
    if (idx < N_C1) {
        int k = idx >> 9, p = idx & 511;
        float v = 0.f;
        if (k < H) v = (p < 256) ? W12[p * H + k] : W11[(p - 256) * H + k];
        C1[idx] = f2b(v);
        return;
    }
    idx -= N_C1;
    if (idx < N_C2) {
        int k = idx / 288, p = idx - k * 288;
        float v = 0.f;
        if (k < H) {
            if (p < 256) v = W22[p * H + k];
            else if (p - 256 < D_OUT) v = Wo[(p - 256) * H + k];
        }
        C2[idx] = f2b(v);
        return;
    }
    idx -= N_C2;
    if (idx < N_WP) {
        int h = idx / 704, k = idx - h * 704;
        Wi1p[idx] = (k < D_IN) ? f2b(Wi1[h * D_IN + k]) : (unsigned short)0;
    }
}

// ---------------------------------------------------------------------------
// Track-A gather (C1, 1KB rows, lane owns 8 cols) — R8-proven, unchanged.
// ---------------------------------------------------------------------------
static __device__ __forceinline__ void ld8b(const unsigned* __restrict__ L, int c,
                                            const unsigned short* __restrict__ Cb,
                                            unsigned l8, u32x4* b) {
    uint4 ia = *(const uint4*)(L + c);
    uint4 ib = *(const uint4*)(L + c + 4);
    unsigned I[8] = {ia.x, ia.y, ia.z, ia.w, ib.x, ib.y, ib.z, ib.w};
#pragma unroll
    for (int jj = 0; jj < 8; ++jj)
        b[jj] = *(const u32x4*)(Cb + ((unsigned)I[jj] << 9) + l8);
}

static __device__ __forceinline__ void acc8b(const u32x4* b, v2f* a) {
#pragma unroll
    for (int jj = 0; jj < 8; ++jj) {
#pragma unroll
        for (int q = 0; q < 4; ++q) {
            unsigned u = b[jj][q];
            v2f t;
            t.x = __uint_as_float(u << 16);
            t.y = __uint_as_float(u & 0xffff0000u);
            a[q] += t;
        }
    }
}

static __device__ __forceinline__ void gatherB(const unsigned* __restrict__ L, int n,
                                               const unsigned short* __restrict__ Cb,
                                               unsigned l8, v2f* a) {
    a[0] = (v2f)(0.f); a[1] = (v2f)(0.f); a[2] = (v2f)(0.f); a[3] = (v2f)(0.f);
    int nr = (n + 7) & ~7;
    if (nr == 0) return;
    u32x4 x[8], y[8];
    ld8b(L, 0, Cb, l8, x);
    if (nr == 8) { acc8b(x, a); return; }
    ld8b(L, 8, Cb, l8, y);
    int c = 16;
    for (; c + 16 <= nr; c += 16) {
        acc8b(x, a); ld8b(L, c, Cb, l8, x);
        acc8b(y, a); ld8b(L, c + 8, Cb, l8, y);
    }
    if (nr - c == 8) {
        acc8b(x, a); ld8b(L, c, Cb, l8, x);
        acc8b(y, a); acc8b(x, a);
    } else {
        acc8b(x, a); acc8b(y, a);
    }
}

// ---------------------------------------------------------------------------
// Track-B gather (compacted C2, 576B rows): lane reads uint2 (its 4 g22
// cols); quad-0 lanes read one aux dword (2 of the 32 aO cols).
// ---------------------------------------------------------------------------
static __device__ __forceinline__ void ld8c(const unsigned* __restrict__ L, int c,
                                            const unsigned short* __restrict__ Cb,
                                            unsigned mo, unsigned ao,
                                            uint2* m, unsigned* av) {
    uint4 ia = *(const uint4*)(L + c);
    uint4 ib = *(const uint4*)(L + c + 4);
    unsigned I[8] = {ia.x, ia.y, ia.z, ia.w, ib.x, ib.y, ib.z, ib.w};
#pragma unroll
    for (int jj = 0; jj < 8; ++jj) {
        const unsigned short* p = Cb + (unsigned)I[jj] * 288u;
        m[jj] = *(const uint2*)(p + mo);
        av[jj] = *(const unsigned*)(p + ao);
    }
}

static __device__ __forceinline__ void acc8c(const uint2* m, const unsigned* av,
                                             v2f* g, v2f& aA) {
#pragma unroll
    for (int jj = 0; jj < 8; ++jj) {
        unsigned u0 = m[jj].x, u1 = m[jj].y, uA = av[jj];
        v2f t0, t1, tA;
        t0.x = __uint_as_float(u0 << 16); t0.y = __uint_as_float(u0 & 0xffff0000u);
        t1.x = __uint_as_float(u1 << 16); t1.y = __uint_as_float(u1 & 0xffff0000u);
        tA.x = __uint_as_float(uA << 16); tA.y = __uint_as_float(uA & 0xffff0000u);
        g[0] += t0; g[1] += t1; aA += tA;
    }
}

static __device__ __forceinline__ void gather2(const unsigned* __restrict__ L, int n,
                                               const unsigned short* __restrict__ Cb,
                                               unsigned mo, unsigned ao,
                                               v2f* g, v2f& aA) {
    g[0] = (v2f)(0.f); g[1] = (v2f)(0.f); aA = (v2f)(0.f);
    int nr = (n + 7) & ~7;
    if (nr == 0) return;
    uint2 xm[8], ym[8]; unsigned xa[8], ya[8];
    ld8c(L, 0, Cb, mo, ao, xm, xa);
    if (nr == 8) { acc8c(xm, xa, g, aA); return; }
    ld8c(L, 8, Cb, mo, ao, ym, ya);
    int c = 16;
    for (; c + 16 <= nr; c += 16) {
        acc8c(xm, xa, g, aA); ld8c(L, c, Cb, mo, ao, xm, xa);
        acc8c(ym, ya, g, aA); ld8c(L, c + 8, Cb, mo, ao, ym, ya);
    }
    if (nr - c == 8) {
        acc8c(xm, xa, g, aA); ld8c(L, c, Cb, mo, ao, xm, xa);
        acc8c(ym, ya, g, aA); acc8c(xm, xa, g, aA);
    } else {
        acc8c(xm, xa, g, aA); acc8c(ym, ya, g, aA);
    }
}

// ---------------------------------------------------------------------------
// Recurrent + JIT-U: one BLOCK (8 waves, 512 threads) per batch element.
// Waves 0-3 = track A (layer 1, step t), waves 4-7 = track B (layer 2, t-1;
// wave 4 also output chain at t-2). All waves contribute 2 col-tiles of the
// next 16-step U chunk via MFMA, spread over the windows.
// ---------------------------------------------------------------------------
__global__ __launch_bounds__(512, 1) void recurrent_k(
    const float* __restrict__ x,
    const unsigned short* __restrict__ Wi1p,
    const float* __restrict__ bi1,
    const float* __restrict__ mem1_0, const float* __restrict__ mem2_0,
    const float* __restrict__ memo_0,
    const float* __restrict__ b11v, const float* __restrict__ b12v,
    const float* __restrict__ b22v, const float* __restrict__ bov,
    const float* __restrict__ tau_adp_h1, const float* __restrict__ tau_adp_h2,
    const float* __restrict__ tau_m_h1, const float* __restrict__ tau_m_h2,
    const float* __restrict__ tau_m_o,
    const unsigned short* __restrict__ C1b, const unsigned short* __restrict__ C2b,
    float* __restrict__ out)
{
    const int tid = threadIdx.x;
    const int lane = tid & 63;
    const int w = tid >> 6;           // 0..7
    const bool trackA = (w < 4);
    const int wt = w & 3;             // wave-in-track
    const int bi = blockIdx.x;
    const int j = wt * 64 + lane;     // owned neuron (both layers)
    const unsigned l8 = (unsigned)lane * 8;          // C1 shorts offset (8 cols)
    const unsigned mo = (unsigned)lane * 4;          // C2 main shorts offset (4 cols)
    const unsigned ao = 256u + 2u * (unsigned)(lane & 15);  // C2 aux shorts offset
    const int quad = lane >> 4;
    const int nl = lane & 15;

    __shared__ float PA[4][2][640];
    __shared__ float PB[4][3][432];
    __shared__ float Ubuf[2][16][260];
    __shared__ __align__(16) unsigned lists[8][128];

    for (int i = tid; i < 4 * 2 * 640; i += 512) ((float*)PA)[i] = 0.f;
    for (int i = tid; i < 4 * 3 * 432; i += 512) ((float*)PB)[i] = 0.f;

    // ---- track A state (layer 1) ----
    float mem1 = 0.f, b1 = 0.01f, spk1 = 0.f;
    float al1 = 0.f, ro1 = 0.f, oma1 = 0.f, omr1 = 0.f, b11p = 0.f;
    if (trackA) {
        mem1 = mem1_0[bi * H + j];
        al1 = __expf(-1.f / tau_m_h1[j]);
        ro1 = __expf(-1.f / tau_adp_h1[j]);
        oma1 = 1.f - al1; omr1 = 1.f - ro1;
        b11p = b11v[j];
    }

    // ---- track B state (layer 2) ----
    float mem2 = 0.f, b2 = 0.01f, spk2 = 0.f;
    float al2 = 0.f, ro2 = 0.f, oma2 = 0.f, omr2 = 0.f, bs2 = 0.f;
    if (!trackA) {
        mem2 = mem2_0[bi * H + j];
        al2 = __expf(-1.f / tau_m_h2[j]);
        ro2 = __expf(-1.f / tau_adp_h2[j]);
        oma2 = 1.f - al2; omr2 = 1.f - ro2;
        bs2 = b12v[j] + b22v[j];
    }

    // ---- wave-4 output state ----
    float memo = 0.f, alo = 0.f, omo = 0.f, bop = 0.f, acco = 0.f;
    const bool outl = (w == 4 && lane < D_OUT);
    if (outl) {
        memo = memo_0[bi * D_OUT + lane];
        alo = __expf(-1.f / tau_m_o[lane]);
        omo = 1.f - alo;
        bop = bov[lane];
    }

    // ---- JIT-U state: this wave owns U cols [32w, 32w+32) as 2 col-tiles ----
    f32x4 uacc[2];
    uacc[0] = (f32x4)(0.f); uacc[1] = (f32x4)(0.f);
    float ubias[2];
    ubias[0] = bi1[w * 32 + nl];
    ubias[1] = bi1[w * 32 + 16 + nl];
    const float* xb = x + (size_t)bi * T * D_IN;

    // Prologue: compute U chunk 0 (steps 0..15) into Ubuf[0].
    {
#pragma unroll 1
        for (int kc = 0; kc < 22; ++kc) {
            int ka = kc * 32 + quad * 8;
            int ka2 = (ka + 4 <= 696) ? ka + 4 : 696;
            const float* xrow = xb + (size_t)nl * D_IN;
            float4 q0 = *(const float4*)(xrow + ka);
            float4 q1 = *(const float4*)(xrow + ka2);
            bf16x8 af;
            af[0] = (short)f2b(q0.x); af[1] = (short)f2b(q0.y);
            af[2] = (short)f2b(q0.z); af[3] = (short)f2b(q0.w);
            af[4] = (short)f2b(q1.x); af[5] = (short)f2b(q1.y);
            af[6] = (short)f2b(q1.z); af[7] = (short)f2b(q1.w);
#pragma unroll
            for (int tt = 0; tt < 2; ++tt) {
                bf16x8 bfv = *(const bf16x8*)(Wi1p + (size_t)(w * 32 + tt * 16 + nl) * 704 + ka);
                uacc[tt] = __builtin_amdgcn_mfma_f32_16x16x32_bf16(af, bfv, uacc[tt], 0, 0, 0);
            }
        }
#pragma unroll
        for (int tt = 0; tt < 2; ++tt)
#pragma unroll
            for (int r = 0; r < 4; ++r)
                Ubuf[0][quad * 4 + r][w * 32 + tt * 16 + nl] = uacc[tt][r] + ubias[tt];
        uacc[0] = (f32x4)(0.f); uacc[1] = (f32x4)(0.f);
    }
    __syncthreads();

    const unsigned long long below = (1ull << lane) - 1ull;
    const int pidx_self = 320 + PIDX(j);    // PIDX(256+j) in PA (g11)
    const int pidx_j = PIDX(j);             // g12 in PA
    const int qidx_j = QIDX(j);             // g22 in PB
    const int qidx_out = 384 + 6 * (lane >> 2) + (lane & 3);  // QIDX(256+lane)

    for (int t = 0; t < 252; ++t) {
        const int rbA = (t + 1) & 1;
        const int wbA = t & 1;
        const int rsB = (t + 1) % 3;
        const int wsB = (t + 2) % 3;

        if (trackA && t < 250) {
            float g11 = PA[0][rbA][pidx_self] + PA[1][rbA][pidx_self] +
                        PA[2][rbA][pidx_self] + PA[3][rbA][pidx_self];
            float u = Ubuf[(t >> 4) & 1][t & 15][j];
            float h1 = u + b11p + g11;
            b1 = ro1 * b1 + omr1 * spk1;
            float B1 = 0.01f + 1.8f * b1;
            mem1 = mem1 * al1 + oma1 * h1 - B1 * spk1;
            spk1 = (mem1 - B1 > 0.f) ? 1.f : 0.f;

            unsigned long long m = __ballot(spk1 != 0.f);
            int n = __popcll(m);
            unsigned* L = lists[w];
            if (spk1 != 0.f) L[__popcll(m & below)] = (unsigned)j;
            L[n + lane] = 256u;
            asm volatile("s_waitcnt lgkmcnt(0)" ::: "memory");
            __builtin_amdgcn_wave_barrier();

            v2f a[4];
            gatherB(L, n, C1b, l8, a);

            float* pw = &PA[wt][wbA][10 * lane];
            *(v2f*)(pw + 0) = a[0];
            *(v2f*)(pw + 2) = a[1];
            *(v2f*)(pw + 4) = a[2];
            *(v2f*)(pw + 6) = a[3];
        }

        if (w == 4 && t >= 2) {
            float e = 0.f;
            if (lane < D_OUT) {
                float aO = PB[0][rsB][qidx_out] + PB[1][rsB][qidx_out] +
                           PB[2][rsB][qidx_out] + PB[3][rsB][qidx_out];
                memo = memo * alo + omo * (bop + aO);
                e = __expf(memo);
            }
            if (t >= 13) {
                float s = e;
#pragma unroll
                for (int dd = 16; dd >= 1; dd >>= 1) s += __shfl_xor(s, dd, 32);
                if (lane < D_OUT) acco += __fdividef(e, s);
            }
        }

        if (!trackA && t >= 1 && t < 251) {
            float g12 = PA[0][rbA][pidx_j] + PA[1][rbA][pidx_j] +
                        PA[2][rbA][pidx_j] + PA[3][rbA][pidx_j];
            float g22 = PB[0][rsB][qidx_j] + PB[1][rsB][qidx_j] +
                        PB[2][rsB][qidx_j] + PB[3][rsB][qidx_j];
            float h2 = bs2 + g22 + g12;
            b2 = ro2 * b2 + omr2 * spk2;
            float B2 = 0.01f + 1.8f * b2;
            mem2 = mem2 * al2 + oma2 * h2 - B2 * spk2;
            spk2 = (mem2 - B2 > 0.f) ? 1.f : 0.f;

            unsigned long long m = __ballot(spk2 != 0.f);
            int n = __popcll(m);
            unsigned* L = lists[w];
            if (spk2 != 0.f) L[__popcll(m & below)] = (unsigned)j;
            L[n + lane] = 256u;
            asm volatile("s_waitcnt lgkmcnt(0)" ::: "memory");
            __builtin_amdgcn_wave_barrier();

            v2f g[2]; v2f aA;
            gather2(L, n, C2b, mo, ao, g, aA);

            float* pw = &PB[wt][wsB][6 * lane];
            *(v2f*)(pw + 0) = g[0];
            *(v2f*)(pw + 2) = g[1];
            if (lane < 16) {
                float* pa = &PB[wt][wsB][384 + 6 * (lane >> 1) + 2 * (lane & 1)];
                *(v2f*)pa = aA;
            }
        }

        // ---- JIT-U: compute chunk (t>>4)+1 spread over this chunk's windows ----
        {
            int c = t >> 4;
            int t0n = (c + 1) << 4;
            if (t < 250 && t0n < 250) {
                int wi = t & 15;
                if (wi < 11) {
#pragma unroll
                    for (int kk = 0; kk < 2; ++kk) {
                        int kc = 2 * wi + kk;
                        int ka = kc * 32 + quad * 8;
                        int ka2 = (ka + 4 <= 696) ? ka + 4 : 696;
                        int row = t0n + nl;
                        bf16x8 af;
                        if (row < 250) {
                            const float* xrow = xb + (size_t)row * D_IN;
                            float4 q0 = *(const float4*)(xrow + ka);
                            float4 q1 = *(const float4*)(xrow + ka2);
                            af[0] = (short)f2b(q0.x); af[1] = (short)f2b(q0.y);
                            af[2] = (short)f2b(q0.z); af[3] = (short)f2b(q0.w);
                            af[4] = (short)f2b(q1.x); af[5] = (short)f2b(q1.y);
                            af[6] = (short)f2b(q1.z); af[7] = (short)f2b(q1.w);
                        } else {
#pragma unroll
                            for (int z = 0; z < 8; ++z) af[z] = 0;
                        }
#pragma unroll
                        for (int tt = 0; tt < 2; ++tt) {
                            bf16x8 bfv = *(const bf16x8*)(Wi1p + (size_t)(w * 32 + tt * 16 + nl) * 704 + ka);
                            uacc[tt] = __builtin_amdgcn_mfma_f32_16x16x32_bf16(af, bfv, uacc[tt], 0, 0, 0);
                        }
                    }
                } else if (wi == 11) {
                    int nb = (c + 1) & 1;
#pragma unroll
                    for (int tt = 0; tt < 2; ++tt)
#pragma unroll
                        for (int r = 0; r < 4; ++r)
                            Ubuf[nb][quad * 4 + r][w * 32 + tt * 16 + nl] = uacc[tt][r] + ubias[tt];
                    uacc[0] = (f32x4)(0.f); uacc[1] = (f32x4)(0.f);
                }
            }
        }

        bar();   // single barrier per window
    }

    if (outl) out[bi * D_OUT + lane] = acco;
}

// ---------------------------------------------------------------------------
extern "C" void kernel_launch(void* const* d_in, const int* in_sizes, int n_in,
                              void* d_out, int out_size, void* d_ws, size_t ws_size,
                              hipStream_t stream) {
    const float* x          = (const float*)d_in[0];
    const float* mem1_0     = (const float*)d_in[1];
    const float* mem2_0     = (const float*)d_in[2];
    const float* memo_0     = (const float*)d_in[3];
    const float* Wi1        = (const float*)d_in[4];
    const float* bi1        = (const float*)d_in[5];
    const float* W11        = (const float*)d_in[6];
    const float* b11        = (const float*)d_in[7];
    const float* W12        = (const float*)d_in[8];
    const float* b12        = (const float*)d_in[9];
    const float* W22        = (const float*)d_in[10];
    const float* b22        = (const float*)d_in[11];
    const float* Wo         = (const float*)d_in[12];
    const float* bo         = (const float*)d_in[13];
    const float* tau_adp_h1 = (const float*)d_in[14];
    const float* tau_adp_h2 = (const float*)d_in[15];
    const float* tau_m_h1   = (const float*)d_in[16];
    const float* tau_m_h2   = (const float*)d_in[17];
    const float* tau_m_o    = (const float*)d_in[18];

    unsigned short* C1b  = (unsigned short*)d_ws;       // [257][512] bf16
    unsigned short* C2b  = C1b + N_C1;                  // [257][288] bf16
    unsigned short* Wi1p = C2b + N_C2;                  // [256][704] bf16

    int prep_total = N_C1 + N_C2 + N_WP;
    prep_k<<<(prep_total + 255) / 256, 256, 0, stream>>>(
        Wi1, W11, W12, W22, Wo, Wi1p, C1b, C2b);

    recurrent_k<<<BATCH, 512, 0, stream>>>(x, Wi1p, bi1,
                                           mem1_0, mem2_0, memo_0,
                                           b11, b12, b22, bo,
                                           tau_adp_h1, tau_adp_h2,
                                           tau_m_h1, tau_m_h2, tau_m_o,
                                           C1b, C2b, (float*)d_out);
}

// Round 10
// 393.343 us; speedup vs baseline: 1.4450x; 1.4450x over previous
//
#include <hip/hip_runtime.h>
#include <math.h>

#define BATCH 128
#define T 250
#define D_IN 700
#define H 256
#define D_OUT 20

typedef float v2f __attribute__((ext_vector_type(2)));
typedef __attribute__((ext_vector_type(8))) short bf16x8;
typedef __attribute__((ext_vector_type(4))) float f32x4;
typedef __attribute__((ext_vector_type(4))) unsigned u32x4;

static __device__ __forceinline__ unsigned short f2b(float f) {
    unsigned u = __float_as_uint(f);
    u += 0x7FFFu + ((u >> 16) & 1u);
    return (unsigned short)(u >> 16);
}

// Raw barrier: LDS ordering only (lgkmcnt). No vmcnt drain so global loads
// stay in flight across it.
static __device__ __forceinline__ void bar() {
    asm volatile("s_waitcnt lgkmcnt(0)" ::: "memory");
    __builtin_amdgcn_s_barrier();
    asm volatile("" ::: "memory");
}

// PA partial index (planar C1 cols, 8 f32 per lane at stride 10) — R8-proven.
#define PIDX(c) (10 * ((c) >> 3) + ((c) & 7))
// PB partial index (compacted C2 cols, 4 f32 per lane at stride 6) — R9-proven.
#define QIDX(c) (6 * ((c) >> 2) + ((c) & 3))

// ---------------------------------------------------------------------------
// Workspace layout:
//   U     [32001][256] f32   (pad row: u-prefetch overrun at t=249)
//   C1b   [257][512] bf16    row k: p<256 -> W12T[k][p]; p>=256 -> W11T[k][p-256]
//   C2b   [257][288] bf16    row k: p<256 -> W22T[k][p]; p in [256,276) -> Wo[p-256][k]; else 0
//   Wi1p  [256][704] bf16    cols 700..703 zero (MFMA K-pad)
//   row 256 of C1b/C2b is all-zero (spike-list padding target)
//
// R10 = R8 (proven: two-track skew, wave-own lists, 1 barrier/window, separate
// gemm_u dispatch — JIT-U fusion REVERTED per R9's 2.5x x-traffic blowup) +
//  (a) C2 compaction (R9-proven correct): 576B rows.
//  (b) C2 rows 0..191 staged in LDS: waves 4-6 gather from the LDS port
//      (independent of the per-CU L2 port that bounds the window); only
//      wave 7 (~26 rows) still reads C2 from L2. PB shrunk to 2 slots
//      (write@t -> read@t+1 lifetime) to fit 146KB LDS.
// ---------------------------------------------------------------------------
#define N_C1 (257 * 512)
#define N_C2 (257 * 288)
#define N_WP (256 * 704)

__global__ void prep_k(const float* __restrict__ Wi1, const float* __restrict__ W11,
                       const float* __restrict__ W12, const float* __restrict__ W22,
                       const float* __restrict__ Wo,
                       unsigned short* __restrict__ Wi1p, unsigned short* __restrict__ C1,
                       unsigned short* __restrict__ C2) {
    int idx = blockIdx.x * 256 + threadIdx.x;
    if (idx < N_C1) {
        int k = idx >> 9, p = idx & 511;
        float v = 0.f;
        if (k < H) v = (p < 256) ? W12[p * H + k] : W11[(p - 256) * H + k];
        C1[idx] = f2b(v);
        return;
    }
    idx -= N_C1;
    if (idx < N_C2) {
        int k = idx / 288, p = idx - k * 288;
        float v = 0.f;
        if (k < H) {
            if (p < 256) v = W22[p * H + k];
            else if (p - 256 < D_OUT) v = Wo[(p - 256) * H + k];
        }
        C2[idx] = f2b(v);
        return;
    }
    idx -= N_C2;
    if (idx < N_WP) {
        int h = idx / 704, k = idx - h * 704;
        Wi1p[idx] = (k < D_IN) ? f2b(Wi1[h * D_IN + k]) : (unsigned short)0;
    }
}

// ---------------------------------------------------------------------------
// U = x @ Wi1^T + bi1 via MFMA 16x16x32 bf16 — restored R8 version (proven).
// ---------------------------------------------------------------------------
__global__ __launch_bounds__(256) void gemm_u_k(const float* __restrict__ x,
                                                const unsigned short* __restrict__ Wi1p,
                                                const float* __restrict__ bi1,
                                                float* __restrict__ U) {
    const int lane = threadIdx.x & 63;
    const int wv = threadIdx.x >> 6;
    const int quad = lane >> 4;
    const int nl = lane & 15;
    const int mbase = blockIdx.x * 64 + wv * 16;
    const int m = mbase + nl;

    f32x4 acc[16];
#pragma unroll
    for (int i = 0; i < 16; ++i) acc[i] = (f32x4)(0.f);

    float bias[16];
#pragma unroll
    for (int nt = 0; nt < 16; ++nt) bias[nt] = bi1[nt * 16 + nl];

    const float* xrow = x + (size_t)m * D_IN;
    const unsigned short* brow = Wi1p + nl * 704 + quad * 8;

    for (int k0 = 0; k0 < 704; k0 += 32) {
        int ka = k0 + quad * 8;
        int ka2 = (ka + 4 <= 696) ? ka + 4 : 696;
        float4 q0 = *(const float4*)(xrow + ka);
        float4 q1 = *(const float4*)(xrow + ka2);
        bf16x8 af;
        af[0] = (short)f2b(q0.x); af[1] = (short)f2b(q0.y);
        af[2] = (short)f2b(q0.z); af[3] = (short)f2b(q0.w);
        af[4] = (short)f2b(q1.x); af[5] = (short)f2b(q1.y);
        af[6] = (short)f2b(q1.z); af[7] = (short)f2b(q1.w);

        const unsigned short* bp = brow + k0;
        bf16x8 bf[16];
#pragma unroll
        for (int nt = 0; nt < 16; ++nt)
            bf[nt] = *(const bf16x8*)(bp + nt * 16 * 704);
#pragma unroll
        for (int nt = 0; nt < 16; ++nt)
            acc[nt] = __builtin_amdgcn_mfma_f32_16x16x32_bf16(af, bf[nt], acc[nt], 0, 0, 0);
    }

#pragma unroll
    for (int nt = 0; nt < 16; ++nt) {
#pragma unroll
        for (int r = 0; r < 4; ++r) {
            U[(size_t)(mbase + quad * 4 + r) * H + nt * 16 + nl] = acc[nt][r] + bias[nt];
        }
    }
}

// ---------------------------------------------------------------------------
// Track-A gather (C1, 1KB rows, lane owns 8 cols) — R8-proven, unchanged.
// ---------------------------------------------------------------------------
static __device__ __forceinline__ void ld8b(const unsigned* __restrict__ L, int c,
                                            const unsigned short* __restrict__ Cb,
                                            unsigned l8, u32x4* b) {
    uint4 ia = *(const uint4*)(L + c);
    uint4 ib = *(const uint4*)(L + c + 4);
    unsigned I[8] = {ia.x, ia.y, ia.z, ia.w, ib.x, ib.y, ib.z, ib.w};
#pragma unroll
    for (int jj = 0; jj < 8; ++jj)
        b[jj] = *(const u32x4*)(Cb + ((unsigned)I[jj] << 9) + l8);
}

static __device__ __forceinline__ void acc8b(const u32x4* b, v2f* a) {
#pragma unroll
    for (int jj = 0; jj < 8; ++jj) {
#pragma unroll
        for (int q = 0; q < 4; ++q) {
            unsigned u = b[jj][q];
            v2f t;
            t.x = __uint_as_float(u << 16);
            t.y = __uint_as_float(u & 0xffff0000u);
            a[q] += t;
        }
    }
}

static __device__ __forceinline__ void gatherB(const unsigned* __restrict__ L, int n,
                                               const unsigned short* __restrict__ Cb,
                                               unsigned l8, v2f* a) {
    a[0] = (v2f)(0.f); a[1] = (v2f)(0.f); a[2] = (v2f)(0.f); a[3] = (v2f)(0.f);
    int nr = (n + 7) & ~7;
    if (nr == 0) return;
    u32x4 x[8], y[8];
    ld8b(L, 0, Cb, l8, x);
    if (nr == 8) { acc8b(x, a); return; }
    ld8b(L, 8, Cb, l8, y);
    int c = 16;
    for (; c + 16 <= nr; c += 16) {
        acc8b(x, a); ld8b(L, c, Cb, l8, x);
        acc8b(y, a); ld8b(L, c + 8, Cb, l8, y);
    }
    if (nr - c == 8) {
        acc8b(x, a); ld8b(L, c, Cb, l8, x);
        acc8b(y, a); acc8b(x, a);
    } else {
        acc8b(x, a); acc8b(y, a);
    }
}

// ---------------------------------------------------------------------------
// Track-B gather (compacted 576B rows; global OR LDS source — forceinline
// specializes per call site, InferAddressSpaces turns the LDS call's loads
// into ds_read_b64/b32). uint2 main (4 g22 cols) + aux dword (2 aO cols,
// 4x quad broadcast). R9-proven layout.
// ---------------------------------------------------------------------------
static __device__ __forceinline__ void ld8c(const unsigned* __restrict__ L, int c,
                                            const unsigned short* Cb,
                                            unsigned mo, unsigned ao,
                                            uint2* m, unsigned* av) {
    uint4 ia = *(const uint4*)(L + c);
    uint4 ib = *(const uint4*)(L + c + 4);
    unsigned I[8] = {ia.x, ia.y, ia.z, ia.w, ib.x, ib.y, ib.z, ib.w};
#pragma unroll
    for (int jj = 0; jj < 8; ++jj) {
        const unsigned short* p = Cb + (unsigned)I[jj] * 288u;
        m[jj] = *(const uint2*)(p + mo);
        av[jj] = *(const unsigned*)(p + ao);
    }
}

static __device__ __forceinline__ void acc8c(const uint2* m, const unsigned* av,
                                             v2f* g, v2f& aA) {
#pragma unroll
    for (int jj = 0; jj < 8; ++jj) {
        unsigned u0 = m[jj].x, u1 = m[jj].y, uA = av[jj];
        v2f t0, t1, tA;
        t0.x = __uint_as_float(u0 << 16); t0.y = __uint_as_float(u0 & 0xffff0000u);
        t1.x = __uint_as_float(u1 << 16); t1.y = __uint_as_float(u1 & 0xffff0000u);
        tA.x = __uint_as_float(uA << 16); tA.y = __uint_as_float(uA & 0xffff0000u);
        g[0] += t0; g[1] += t1; aA += tA;
    }
}

static __device__ __forceinline__ void gather2(const unsigned* __restrict__ L, int n,
                                               const unsigned short* Cb,
                                               unsigned mo, unsigned ao,
                                               v2f* g, v2f& aA) {
    g[0] = (v2f)(0.f); g[1] = (v2f)(0.f); aA = (v2f)(0.f);
    int nr = (n + 7) & ~7;
    if (nr == 0) return;
    uint2 xm[8], ym[8]; unsigned xa[8], ya[8];
    ld8c(L, 0, Cb, mo, ao, xm, xa);
    if (nr == 8) { acc8c(xm, xa, g, aA); return; }
    ld8c(L, 8, Cb, mo, ao, ym, ya);
    int c = 16;
    for (; c + 16 <= nr; c += 16) {
        acc8c(xm, xa, g, aA); ld8c(L, c, Cb, mo, ao, xm, xa);
        acc8c(ym, ya, g, aA); ld8c(L, c + 8, Cb, mo, ao, ym, ya);
    }
    if (nr - c == 8) {
        acc8c(xm, xa, g, aA); ld8c(L, c, Cb, mo, ao, xm, xa);
        acc8c(ym, ya, g, aA); acc8c(xm, xa, g, aA);
    } else {
        acc8c(xm, xa, g, aA); acc8c(ym, ya, g, aA);
    }
}

// ---------------------------------------------------------------------------
// Recurrent: one BLOCK (8 waves, 512 threads) per batch element.
// Waves 0-3 = track A (layer 1, step t), waves 4-7 = track B (layer 2, t-1;
// wave 4 also output chain at t-2). Waves 4-6 gather C2 from LDS (rows
// 0..191 staged; pad row 192 = zeros); wave 7 gathers rows 192..255 from
// global. One barrier per window.
// ---------------------------------------------------------------------------
__global__ __launch_bounds__(512, 1) void recurrent_k(
    const float* __restrict__ U,
    const float* __restrict__ mem1_0, const float* __restrict__ mem2_0,
    const float* __restrict__ memo_0,
    const float* __restrict__ b11v, const float* __restrict__ b12v,
    const float* __restrict__ b22v, const float* __restrict__ bov,
    const float* __restrict__ tau_adp_h1, const float* __restrict__ tau_adp_h2,
    const float* __restrict__ tau_m_h1, const float* __restrict__ tau_m_h2,
    const float* __restrict__ tau_m_o,
    const unsigned short* __restrict__ C1b, const unsigned short* __restrict__ C2b,
    float* __restrict__ out)
{
    const int tid = threadIdx.x;
    const int lane = tid & 63;
    const int w = tid >> 6;           // 0..7
    const bool trackA = (w < 4);
    const int wt = w & 3;             // wave-in-track
    const int bi = blockIdx.x;
    const int j = wt * 64 + lane;     // owned neuron (both layers)
    const unsigned l8 = (unsigned)lane * 8;          // C1 shorts offset (8 cols)
    const unsigned mo = (unsigned)lane * 4;          // C2 main shorts offset
    const unsigned ao = 256u + 2u * (unsigned)(lane & 15);  // C2 aux shorts offset

    __shared__ float PA[4][2][640];                    // 20480 B
    __shared__ float PB[4][2][432];                    // 13824 B
    __shared__ __align__(16) unsigned short C2L[193 * 288];  // 111168 B
    __shared__ __align__(16) unsigned lists[8][128];   // 4096 B

    // ---- stage C2 rows 0..191 into LDS (+ zero row 192) ----
    {
        unsigned* dst = (unsigned*)C2L;
        const unsigned* src = (const unsigned*)C2b;
        for (int i = tid; i < 193 * 144; i += 512)
            dst[i] = (i < 192 * 144) ? src[i] : 0u;
    }
    for (int i = tid; i < 4 * 2 * 640; i += 512) ((float*)PA)[i] = 0.f;
    for (int i = tid; i < 4 * 2 * 432; i += 512) ((float*)PB)[i] = 0.f;

    // ---- track A state (layer 1) ----
    float mem1 = 0.f, b1 = 0.01f, spk1 = 0.f;
    float al1 = 0.f, ro1 = 0.f, oma1 = 0.f, omr1 = 0.f, b11p = 0.f;
    if (trackA) {
        mem1 = mem1_0[bi * H + j];
        al1 = __expf(-1.f / tau_m_h1[j]);
        ro1 = __expf(-1.f / tau_adp_h1[j]);
        oma1 = 1.f - al1; omr1 = 1.f - ro1;
        b11p = b11v[j];
    }

    // ---- track B state (layer 2) ----
    float mem2 = 0.f, b2 = 0.01f, spk2 = 0.f;
    float al2 = 0.f, ro2 = 0.f, oma2 = 0.f, omr2 = 0.f, bs2 = 0.f;
    if (!trackA) {
        mem2 = mem2_0[bi * H + j];
        al2 = __expf(-1.f / tau_m_h2[j]);
        ro2 = __expf(-1.f / tau_adp_h2[j]);
        oma2 = 1.f - al2; omr2 = 1.f - ro2;
        bs2 = b12v[j] + b22v[j];
    }

    // ---- wave-4 output state ----
    float memo = 0.f, alo = 0.f, omo = 0.f, bop = 0.f, acco = 0.f;
    const bool outl = (w == 4 && lane < D_OUT);
    if (outl) {
        memo = memo_0[bi * D_OUT + lane];
        alo = __expf(-1.f / tau_m_o[lane]);
        omo = 1.f - alo;
        bop = bov[lane];
    }

    const float* Up = U + (size_t)bi * T * H + j;
    float u_cur = trackA ? *Up : 0.f;
    float u_nxt = 0.f;
    const unsigned long long below = (1ull << lane) - 1ull;

    const int pidx_self = 320 + PIDX(j);    // PIDX(256+j) in PA (g11)
    const int pidx_j = PIDX(j);             // g12 in PA
    const int qidx_j = QIDX(j);             // g22 in PB
    const int qidx_out = 384 + 6 * (lane >> 2) + (lane & 3);  // QIDX(256+lane)

    __syncthreads();

    for (int t = 0; t < 252; ++t) {
        const int rbA = (t + 1) & 1;
        const int wbA = t & 1;
        const int rsB = (t + 1) & 1;     // PB slot written at t-1, read here
        const int wsB = t & 1;

        if (trackA && t < 250) {
            float g11 = PA[0][rbA][pidx_self] + PA[1][rbA][pidx_self] +
                        PA[2][rbA][pidx_self] + PA[3][rbA][pidx_self];
            float h1 = u_cur + b11p + g11;
            b1 = ro1 * b1 + omr1 * spk1;
            float B1 = 0.01f + 1.8f * b1;
            mem1 = mem1 * al1 + oma1 * h1 - B1 * spk1;
            spk1 = (mem1 - B1 > 0.f) ? 1.f : 0.f;

            unsigned long long m = __ballot(spk1 != 0.f);
            int n = __popcll(m);
            unsigned* L = lists[w];
            if (spk1 != 0.f) L[__popcll(m & below)] = (unsigned)j;
            L[n + lane] = 256u;          // pads -> all-zero global row
            asm volatile("s_waitcnt lgkmcnt(0)" ::: "memory");
            __builtin_amdgcn_wave_barrier();

            u_nxt = Up[H];               // pad row covers t=249 overrun
            Up += H;

            v2f a[4];
            gatherB(L, n, C1b, l8, a);

            float* pw = &PA[wt][wbA][10 * lane];
            *(v2f*)(pw + 0) = a[0];
            *(v2f*)(pw + 2) = a[1];
            *(v2f*)(pw + 4) = a[2];
            *(v2f*)(pw + 6) = a[3];
            u_cur = u_nxt;
        }

        if (w == 4 && t >= 2) {
            // output chain for step s = t-2
            float e = 0.f;
            if (lane < D_OUT) {
                float aO = PB[0][rsB][qidx_out] + PB[1][rsB][qidx_out] +
                           PB[2][rsB][qidx_out] + PB[3][rsB][qidx_out];
                memo = memo * alo + omo * (bop + aO);
                e = __expf(memo);
            }
            if (t >= 13) {
                float s = e;
#pragma unroll
                for (int dd = 16; dd >= 1; dd >>= 1) s += __shfl_xor(s, dd, 32);
                if (lane < D_OUT) acco += __fdividef(e, s);
            }
        }

        if (!trackA && t >= 1 && t < 251) {
            // update2(t-1): g12 from G1(t-1), g22 from G2(t-2)
            float g12 = PA[0][rbA][pidx_j] + PA[1][rbA][pidx_j] +
                        PA[2][rbA][pidx_j] + PA[3][rbA][pidx_j];
            float g22 = PB[0][rsB][qidx_j] + PB[1][rsB][qidx_j] +
                        PB[2][rsB][qidx_j] + PB[3][rsB][qidx_j];
            float h2 = bs2 + g22 + g12;
            b2 = ro2 * b2 + omr2 * spk2;
            float B2 = 0.01f + 1.8f * b2;
            mem2 = mem2 * al2 + oma2 * h2 - B2 * spk2;
            spk2 = (mem2 - B2 > 0.f) ? 1.f : 0.f;

            unsigned long long m = __ballot(spk2 != 0.f);
            int n = __popcll(m);
            unsigned* L = lists[w];
            if (spk2 != 0.f) L[__popcll(m & below)] = (unsigned)j;
            L[n + lane] = (wt == 3) ? 256u : 192u;   // pads: global / LDS zero row
            asm volatile("s_waitcnt lgkmcnt(0)" ::: "memory");
            __builtin_amdgcn_wave_barrier();

            v2f g[2]; v2f aA;
            if (wt == 3) {
                gather2(L, n, C2b, mo, ao, g, aA);        // global (rows 192..255)
            } else {
                gather2(L, n, (const unsigned short*)C2L, mo, ao, g, aA);  // LDS
            }

            float* pw = &PB[wt][wsB][6 * lane];
            *(v2f*)(pw + 0) = g[0];
            *(v2f*)(pw + 2) = g[1];
            if (lane < 16) {
                float* pa = &PB[wt][wsB][384 + 6 * (lane >> 1) + 2 * (lane & 1)];
                *(v2f*)pa = aA;
            }
        }

        bar();   // single barrier per window
    }

    if (outl) out[bi * D_OUT + lane] = acco;
}

// ---------------------------------------------------------------------------
extern "C" void kernel_launch(void* const* d_in, const int* in_sizes, int n_in,
                              void* d_out, int out_size, void* d_ws, size_t ws_size,
                              hipStream_t stream) {
    const float* x          = (const float*)d_in[0];
    const float* mem1_0     = (const float*)d_in[1];
    const float* mem2_0     = (const float*)d_in[2];
    const float* memo_0     = (const float*)d_in[3];
    const float* Wi1        = (const float*)d_in[4];
    const float* bi1        = (const float*)d_in[5];
    const float* W11        = (const float*)d_in[6];
    const float* b11        = (const float*)d_in[7];
    const float* W12        = (const float*)d_in[8];
    const float* b12        = (const float*)d_in[9];
    const float* W22        = (const float*)d_in[10];
    const float* b22        = (const float*)d_in[11];
    const float* Wo         = (const float*)d_in[12];
    const float* bo         = (const float*)d_in[13];
    const float* tau_adp_h1 = (const float*)d_in[14];
    const float* tau_adp_h2 = (const float*)d_in[15];
    const float* tau_m_h1   = (const float*)d_in[16];
    const float* tau_m_h2   = (const float*)d_in[17];
    const float* tau_m_o    = (const float*)d_in[18];

    float* U = (float*)d_ws;                                       // [32001][256] f32
    unsigned short* C1b  = (unsigned short*)(U + ((size_t)BATCH * T + 1) * H);
    unsigned short* C2b  = C1b + N_C1;                  // [257][288] bf16
    unsigned short* Wi1p = C2b + N_C2;                  // [256][704] bf16

    int prep_total = N_C1 + N_C2 + N_WP;
    prep_k<<<(prep_total + 255) / 256, 256, 0, stream>>>(
        Wi1, W11, W12, W22, Wo, Wi1p, C1b, C2b);

    gemm_u_k<<<(BATCH * T) / 64, 256, 0, stream>>>(x, Wi1p, bi1, U);

    recurrent_k<<<BATCH, 512, 0, stream>>>(U, mem1_0, mem2_0, memo_0,
                                           b11, b12, b22, bo,
                                           tau_adp_h1, tau_adp_h2,
                                           tau_m_h1, tau_m_h2, tau_m_o,
                                           C1b, C2b, (float*)d_out);
}